// Round 3
// baseline (216.936 us; speedup 1.0000x reference)
//
#include <hip/hip_runtime.h>

// Problem constants
#define B_DIM 32
#define V_DIM 21
#define D_DIM 512
#define P_DIM 64
#define M_TOTAL 672          // B*V
#define K_TOTAL 32768        // D*P
#define OUT_DIM 96
#define E_DIM 8
#define R_DIM 8
#define H_DIM 256
#define N_TOTAL 160          // OUT_DIM + E*R
#define SCALING 2.0f
#define POOL_SCALE (1.0f / (V_DIM * (float)P_DIM))

// GEMM tiling
#define BM 64
#define BK 32
#define KSPLIT 32
#define K_PER_SPLIT (K_TOTAL / KSPLIT)   // 1024
#define CHUNKS (K_PER_SPLIT / BK)        // 32
#define SMN (M_TOTAL * N_TOTAL)          // 107520 per partial plane
#define NMB 11                           // m-blocks
#define RC_ROWS 4                        // rows per reduce_combine block

typedef __attribute__((ext_vector_type(4))) float floatx4;
typedef __attribute__((ext_vector_type(8))) short short8;
typedef __attribute__((ext_vector_type(2))) unsigned int uintx2;

// v_cvt_pk_bf16_f32: RNE, lo -> bits[15:0], hi -> bits[31:16]
__device__ __forceinline__ unsigned int cvt_pk_bf16(float lo, float hi) {
  unsigned int r;
  asm("v_cvt_pk_bf16_f32 %0, %1, %2" : "=v"(r) : "v"(lo), "v"(hi));
  return r;
}

// async 16B global->LDS; lds ptr must be wave-uniform (HW adds lane*16)
__device__ __forceinline__ void gl_lds16(const void* g, void* l) {
  __builtin_amdgcn_global_load_lds(
      (const __attribute__((address_space(1))) void*)g,
      (__attribute__((address_space(3))) void*)l, 16, 0, 0);
}

// ------- gemm v3: convW fused away. A: async fp32->LDS (swizzled source),
// converted to bf16 in-register at MFMA time. B (=[W_base|lora_A] rows):
// reg-staged fp32 -> cvt_pk bf16 -> swizzled ds_write (T14 split: loads issued
// at loop top, LDS write after compute). Pooling from fp32 A tile; per-block
// pooled partials stored non-atomically to pp[mb][5][512] (unique owner).
// LDS 36.6KB -> 4 blocks/CU; grid 11x32.
__global__ __launch_bounds__(256, 4)
void gemm_kernel(const float* __restrict__ x, const float* __restrict__ W_base,
                 const float* __restrict__ lora_A, float* __restrict__ P,
                 float* __restrict__ pp) {
  __shared__ __attribute__((aligned(16))) float ldsA[2][BM * BK];       // 2 x 8 KB
  __shared__ __attribute__((aligned(16))) short ldsB[2][N_TOTAL * BK];  // 2 x 10 KB
  __shared__ float lds_pool[5 * 16];      // [b_local][d_local]

  const int tid = threadIdx.x;
  const int mb = blockIdx.x;
  const int m0 = mb * BM;
  const int ky = blockIdx.y;
  const int kbase = ky * K_PER_SPLIT;
  const int lane = tid & 63;
  const int wave = tid >> 6;
  const int quad = lane >> 4;
  const int l16 = lane & 15;
  const int b_first = m0 / V_DIM;
  const int d_first = ky * (K_PER_SPLIT / P_DIM);   // ky*16

  if (tid < 80) lds_pool[tid] = 0.0f;

  // A tile [64 rows][32 f] = 512 x 16B chunks; source chunk XOR-swizzled
  // within the row (slot s of row r holds global chunk s^(r&7)); LDS linear.
  const float* srcA[2]; int dstA[2];
  #pragma unroll
  for (int it = 0; it < 2; ++it) {
    int idx = it * 256 + tid;
    int row = idx >> 3, j = idx & 7;
    int m = m0 + row; if (m > M_TOTAL - 1) m = M_TOTAL - 1;   // clamp OOB rows
    srcA[it] = x + (size_t)m * K_TOTAL + kbase + ((j ^ (row & 7)) << 2);
    dstA[it] = (it * 256 + (tid & 192)) << 2;       // wave-uniform float index
  }

  // B tile [160 rows][32 f] read from fp32 W rows; each thread owns 5 float4
  // slots (row=idx>>3, j=idx&7) and writes the bf16 8B result to the
  // pair-swizzled LDS slot: pair p=row>>1, chunk c8=((row&1)<<2)|(j>>1),
  // slot = c8^(p&7), half = j&1.  Read side uses the same mapping.
  const float* srcB[5]; int offB[5];
  #pragma unroll
  for (int it = 0; it < 5; ++it) {
    int idx = it * 256 + tid;
    int row = idx >> 3, j = idx & 7;
    const float* wrow = (row < OUT_DIM)
        ? (W_base + (size_t)row * K_TOTAL)
        : (lora_A + (size_t)(row - OUT_DIM) * K_TOTAL);
    srcB[it] = wrow + kbase + (j << 2);
    int p = row >> 1;
    int c8 = ((row & 1) << 2) | (j >> 1);
    offB[it] = p * 64 + ((c8 ^ (p & 7)) << 3) + ((j & 1) << 2);  // short index
  }

  // pooling: 4 threads per A-row; slots {(row+part)&7, +4} cover all 8 chunks
  const int prow = tid >> 2;
  const int part = tid & 3;
  const int ps1 = (prow + part) & 7;
  const int ps2 = (ps1 + 4) & 7;
  const int pm = m0 + prow;
  const int pool_base = (pm < M_TOTAL) ? ((pm / V_DIM) - b_first) * 16 : -1;

  floatx4 rb[5];
  floatx4 acc[10];
  #pragma unroll
  for (int nt = 0; nt < 10; ++nt) acc[nt] = (floatx4)(0.0f);

#define BLOAD(c)                                                              \
  { _Pragma("unroll")                                                         \
    for (int it = 0; it < 5; ++it)                                            \
      rb[it] = *(const floatx4*)(srcB[it] + (c) * BK); }
#define AISSUE(c, bb)                                                         \
  { _Pragma("unroll")                                                         \
    for (int it = 0; it < 2; ++it)                                            \
      gl_lds16(srcA[it] + (c) * BK, &ldsA[bb][dstA[it]]); }
#define BWRITE(bb)                                                            \
  { _Pragma("unroll")                                                         \
    for (int it = 0; it < 5; ++it) {                                          \
      uintx2 w;                                                               \
      w[0] = cvt_pk_bf16(rb[it][0], rb[it][1]);                               \
      w[1] = cvt_pk_bf16(rb[it][2], rb[it][3]);                               \
      *(uintx2*)&ldsB[bb][offB[it]] = w;                                      \
    } }

  BLOAD(0); AISSUE(0, 0); BWRITE(0);
  __syncthreads();          // drains A(0) + B writes; lds_pool zeros visible

  #pragma unroll 2
  for (int c = 0; c < CHUNKS; ++c) {
    const int buf = c & 1;
    if (c + 1 < CHUNKS) { BLOAD(c + 1); AISSUE(c + 1, buf ^ 1); }
    // pooling over this chunk's fp32 A tile (swizzle-invariant row sums)
    {
      const floatx4* aT = (const floatx4*)ldsA[buf];
      floatx4 u = aT[prow * 8 + ps1];
      floatx4 w = aT[prow * 8 + ps2];
      float s = ((u[0] + u[1]) + (u[2] + u[3])) + ((w[0] + w[1]) + (w[2] + w[3]));
      s += __shfl_down(s, 2, 4);
      s += __shfl_down(s, 1, 4);
      if (part == 0 && pool_base >= 0)
        atomicAdd(&lds_pool[pool_base + (c >> 1)], s);
    }
    // MFMA: A fragment read via swizzled slots, cvt to bf16 (reused 10x)
    {
      const floatx4* aT = (const floatx4*)ldsA[buf];
      const int r = wave * 16 + l16;
      floatx4 f0 = aT[r * 8 + ((2 * quad) ^ (r & 7))];
      floatx4 f1 = aT[r * 8 + ((2 * quad + 1) ^ (r & 7))];
      union { short8 s; unsigned int u[4]; } av;
      av.u[0] = cvt_pk_bf16(f0[0], f0[1]);
      av.u[1] = cvt_pk_bf16(f0[2], f0[3]);
      av.u[2] = cvt_pk_bf16(f1[0], f1[1]);
      av.u[3] = cvt_pk_bf16(f1[2], f1[3]);
      const short8* bT = (const short8*)ldsB[buf];
      #pragma unroll
      for (int nt = 0; nt < 10; ++nt) {
        int r2 = nt * 16 + l16;
        int pr = r2 >> 1;
        short8 b = bT[pr * 8 + ((((r2 & 1) << 2) | quad) ^ (pr & 7))];
        acc[nt] = __builtin_amdgcn_mfma_f32_16x16x32_bf16(av.s, b, acc[nt], 0, 0, 0);
      }
    }
    if (c + 1 < CHUNKS) BWRITE(buf ^ 1);   // rb holds chunk c+1 here
    __syncthreads();        // drains A(c+1) loads, B writes, all reads of c
  }

  // partial-plane store (D layout: col=lane&15, row=quad*4+reg)
  {
    const int mrow = m0 + wave * 16 + quad * 4;
    float* Pp = P + (size_t)ky * SMN + (size_t)mrow * N_TOTAL + l16;
    #pragma unroll
    for (int r = 0; r < 4; ++r)
      if (mrow + r < M_TOTAL)
        #pragma unroll
        for (int nt = 0; nt < 10; ++nt)
          Pp[(size_t)r * N_TOTAL + nt * 16] = acc[nt][r];
  }

  // pooled partials: unique owner (mb, bl, d) -> plain store, no atomics
  if (tid < 80) {
    int bl = tid >> 4, dl = tid & 15;
    pp[((size_t)(mb * 5 + bl)) * D_DIM + d_first + dl] = lds_pool[tid];
  }
}

// ---------------- router: gather pooled from pp, MLP + softmax + top-2 ------
__global__ __launch_bounds__(256)
void router_kernel(const float* __restrict__ pp, const float* __restrict__ W1,
                   const float* __restrict__ b1, const float* __restrict__ W2,
                   const float* __restrict__ b2, float* __restrict__ wfull,
                   float* __restrict__ probs_out) {
  __shared__ float sp[D_DIM];
  __shared__ float sh[H_DIM];
  __shared__ float slog[E_DIM];
  const int b = blockIdx.x;
  const int t = threadIdx.x;
  // rows of batch b live in m-blocks mb1..mb2 (at most 2)
  const int mb1 = (b * V_DIM) / BM;
  const int mb2 = (b * V_DIM + V_DIM - 1) / BM;
  const int bf1 = (mb1 * BM) / V_DIM;
  const int bf2 = (mb2 * BM) / V_DIM;
  const float* p1 = pp + (size_t)(mb1 * 5 + (b - bf1)) * D_DIM;
  const float* p2 = pp + (size_t)(mb2 * 5 + (b - bf2)) * D_DIM;
  for (int d = t; d < D_DIM; d += 256) {
    float v = p1[d];
    if (mb2 != mb1) v += p2[d];
    sp[d] = v * POOL_SCALE;
  }
  __syncthreads();
  float acc = b1[t];
  const float* w1r = W1 + (size_t)t * D_DIM;
  for (int d = 0; d < D_DIM; ++d) acc += sp[d] * w1r[d];
  sh[t] = fmaxf(acc, 0.0f);
  __syncthreads();
  if (t < E_DIM) {
    float a = b2[t];
    const float* w2r = W2 + t * H_DIM;
    for (int j = 0; j < H_DIM; ++j) a += sh[j] * w2r[j];
    slog[t] = a;
  }
  __syncthreads();
  if (t == 0) {
    float p[E_DIM];
    float mx = slog[0];
    for (int e = 1; e < E_DIM; ++e) mx = fmaxf(mx, slog[e]);
    float se = 0.0f;
    for (int e = 0; e < E_DIM; ++e) { p[e] = __expf(slog[e] - mx); se += p[e]; }
    float inv = 1.0f / se;
    for (int e = 0; e < E_DIM; ++e) { p[e] *= inv; probs_out[b * E_DIM + e] = p[e]; }
    // top-2, lowest index wins ties (strict > keeps earlier index)
    int i0 = 0;
    for (int e = 1; e < E_DIM; ++e) if (p[e] > p[i0]) i0 = e;
    int i1 = (i0 == 0) ? 1 : 0;
    for (int e = 0; e < E_DIM; ++e) if (e != i0 && p[e] > p[i1]) i1 = e;
    float s2 = p[i0] + p[i1];
    float invs = 1.0f / fmaxf(s2, 1e-6f);
    for (int e = 0; e < E_DIM; ++e) {
      float w = 0.0f;
      if (e == i0) w += p[i0] * invs;
      if (e == i1) w += p[i1] * invs;
      wfull[b * E_DIM + e] = w;
    }
  }
}

// ------- reduce partials over KSPLIT + combine: out = S_b + b_base + 2*Σ w·(S_l·B)
__global__ __launch_bounds__(256)
void reduce_combine_kernel(const float* __restrict__ P, const float* __restrict__ b_base,
                           const float* __restrict__ lora_B, const float* __restrict__ wfull,
                           float* __restrict__ out) {
  __shared__ float sS[RC_ROWS * N_TOTAL];   // 640 floats
  const int t = threadIdx.x;
  const int NF4 = RC_ROWS * N_TOTAL / 4;    // 160 float4 per block
  if (t < NF4) {
    const floatx4* P4 = (const floatx4*)P;
    size_t base = (size_t)blockIdx.x * NF4 + t;
    floatx4 a = (floatx4)(0.0f);
    #pragma unroll 8
    for (int k = 0; k < KSPLIT; ++k) a += P4[(size_t)k * (SMN / 4) + base];
    *(floatx4*)&sS[t * 4] = a;
  }
  __syncthreads();
  for (int i = t; i < RC_ROWS * OUT_DIM; i += 256) {
    int mr = i / OUT_DIM;
    int o = i - mr * OUT_DIM;
    int mm = blockIdx.x * RC_ROWS + mr;
    int b = mm / V_DIM;
    const float* srow = sS + mr * N_TOTAL;
    float res = srow[o] + b_base[o];
    float moe = 0.0f;
    #pragma unroll
    for (int e = 0; e < E_DIM; ++e) {
      float we = wfull[b * E_DIM + e];
      if (we != 0.0f) {
        const float* lb = lora_B + ((size_t)e * OUT_DIM + o) * R_DIM;
        float dd = 0.0f;
        #pragma unroll
        for (int r = 0; r < R_DIM; ++r) dd += srow[OUT_DIM + e * R_DIM + r] * lb[r];
        moe += we * dd;
      }
    }
    out[(size_t)mm * OUT_DIM + o] = res + SCALING * moe;
  }
}

extern "C" void kernel_launch(void* const* d_in, const int* in_sizes, int n_in,
                              void* d_out, int out_size, void* d_ws, size_t ws_size,
                              hipStream_t stream) {
  const float* x      = (const float*)d_in[0];
  const float* W_base = (const float*)d_in[1];
  const float* b_base = (const float*)d_in[2];
  const float* W1     = (const float*)d_in[3];
  const float* b1     = (const float*)d_in[4];
  const float* W2     = (const float*)d_in[5];
  const float* b2     = (const float*)d_in[6];
  const float* lora_A = (const float*)d_in[7];
  const float* lora_B = (const float*)d_in[8];
  float* out = (float*)d_out;

  // ws layout: pp[11*5*512 f] | wfull[256 f] | P[32*107520 f]
  float* ws    = (float*)d_ws;
  float* pp    = ws;
  float* wfull = ws + NMB * 5 * D_DIM;
  float* P     = wfull + 256;

  gemm_kernel<<<dim3(NMB, KSPLIT), 256, 0, stream>>>(x, W_base, lora_A, P, pp);
  router_kernel<<<B_DIM, 256, 0, stream>>>(pp, W1, b1, W2, b2, wfull,
                                           out + (size_t)M_TOTAL * OUT_DIM);
  reduce_combine_kernel<<<M_TOTAL / RC_ROWS, 256, 0, stream>>>(
      P, b_base, lora_B, wfull, out);
}

// Round 5
// 215.394 us; speedup vs baseline: 1.0072x; 1.0072x over previous
//
#include <hip/hip_runtime.h>

// Problem constants
#define B_DIM 32
#define V_DIM 21
#define D_DIM 512
#define P_DIM 64
#define M_TOTAL 672          // B*V
#define K_TOTAL 32768        // D*P
#define OUT_DIM 96
#define E_DIM 8
#define R_DIM 8
#define H_DIM 256
#define N_TOTAL 160          // OUT_DIM + E*R
#define SCALING 2.0f
#define POOL_SCALE (1.0f / (V_DIM * (float)P_DIM))

// GEMM tiling: 4-buffer async global->LDS, counted vmcnt (T3/T4), raw s_barrier.
#define BM 64
#define BK 32
#define KSPLIT 32
#define K_PER_SPLIT (K_TOTAL / KSPLIT)   // 1024
#define CHUNKS (K_PER_SPLIT / BK)        // 32
#define SMN (M_TOTAL * N_TOTAL)          // 107520 per partial plane
#define NMB 11                           // m-blocks
#define RC_ROWS 4                        // rows per reduce_combine block

typedef __attribute__((ext_vector_type(4))) float floatx4;
typedef __attribute__((ext_vector_type(8))) short short8;

__device__ __forceinline__ unsigned short f2bf(float f) {
  union { float f; unsigned int u; } v; v.f = f;
  unsigned int u = v.u + (0x7FFFu + ((v.u >> 16) & 1u));  // RNE
  return (unsigned short)(u >> 16);
}

// v_cvt_pk_bf16_f32: RNE, lo -> bits[15:0], hi -> bits[31:16] (matches f2bf)
__device__ __forceinline__ unsigned int cvt_pk_bf16(float lo, float hi) {
  unsigned int r;
  asm("v_cvt_pk_bf16_f32 %0, %1, %2" : "=v"(r) : "v"(lo), "v"(hi));
  return r;
}

// async 16B global->LDS; lds ptr must be wave-uniform (HW adds lane*16)
__device__ __forceinline__ void gl_lds16(const void* g, void* l) {
  __builtin_amdgcn_global_load_lds(
      (const __attribute__((address_space(1))) void*)g,
      (__attribute__((address_space(3))) void*)l, 16, 0, 0);
}

// ------- convW: [W_base|lora_A] fp32 -> bf16 Wb[160][32768]
__global__ __launch_bounds__(256)
void convW_kernel(const float* __restrict__ W_base, const float* __restrict__ lora_A,
                  short* __restrict__ Wb) {
  int gid = blockIdx.x * 256 + threadIdx.x;
  size_t base = (size_t)gid * 8;
  int row = (int)(base >> 15);
  int k = (int)(base & 32767);
  const float* src = (row < OUT_DIM) ? (W_base + ((size_t)row << 15) + k)
                                     : (lora_A + ((size_t)(row - OUT_DIM) << 15) + k);
  floatx4 v0 = ((const floatx4*)src)[0];
  floatx4 v1 = ((const floatx4*)src)[1];
  short8 sv;
  sv[0] = (short)f2bf(v0[0]); sv[1] = (short)f2bf(v0[1]);
  sv[2] = (short)f2bf(v0[2]); sv[3] = (short)f2bf(v0[3]);
  sv[4] = (short)f2bf(v1[0]); sv[5] = (short)f2bf(v1[1]);
  sv[6] = (short)f2bf(v1[2]); sv[7] = (short)f2bf(v1[3]);
  *(short8*)(Wb + base) = sv;
}

// ------- gemm v5: all staging via global_load_lds into 4 LDS buffers,
// lookahead 2. Per chunk: counted s_waitcnt vmcnt(K) (never 0 mid-loop) ->
// s_barrier -> issue chunk c+2 -> compute chunk c. WAR distance on a buffer
// overwrite = 2 barriers. lgkmcnt(0) before the first barrier publishes the
// lds_pool zeros (v4's race). Loop body has ZERO other VMEM ops, so vmcnt
// immediates are exact. LDS 74 KB -> 2 blocks/CU; grid 11x32.
__global__ __launch_bounds__(256, 2)
void gemm_kernel(const float* __restrict__ x, const short* __restrict__ Wb,
                 float* __restrict__ P, float* __restrict__ pp) {
  __shared__ __attribute__((aligned(16))) float ldsA[4][BM * BK];       // 4 x 8 KB
  __shared__ __attribute__((aligned(16))) short ldsB[4][N_TOTAL * BK];  // 4 x 10 KB
  __shared__ float lds_pool[5 * 16];      // [b_local][d_local]

  const int tid = threadIdx.x;
  const int mb = blockIdx.x;
  const int m0 = mb * BM;
  const int ky = blockIdx.y;
  const int kbase = ky * K_PER_SPLIT;
  const int lane = tid & 63;
  const int wave = tid >> 6;
  const int quad = lane >> 4;
  const int l16 = lane & 15;
  const int b_first = m0 / V_DIM;
  const int d_first = ky * (K_PER_SPLIT / P_DIM);   // ky*16

  if (tid < 80) lds_pool[tid] = 0.0f;

  // A tile [64 rows][32 f] = 512 x 16B chunks; source chunk XOR-swizzled
  // within the row (slot s of row r holds global chunk s^(r&7)); LDS linear.
  const float* srcA[2]; int dstA[2];
  #pragma unroll
  for (int it = 0; it < 2; ++it) {
    int idx = it * 256 + tid;
    int row = idx >> 3, j = idx & 7;
    int m = m0 + row; if (m > M_TOTAL - 1) m = M_TOTAL - 1;   // clamp OOB rows
    srcA[it] = x + (size_t)m * K_TOTAL + kbase + ((j ^ (row & 7)) << 2);
    dstA[it] = (it * 256 + (tid & 192)) << 2;       // wave-uniform float index
  }
  // B tile [160 rows][32 bf16] = 80 row-PAIRS of 8x16B chunks; source swizzled
  // by pair: dest slot s8 of pair p holds global chunk c8 = s8^(p&7).
  const short* srcB[3]; int dstB[3];
  #pragma unroll
  for (int it = 0; it < 3; ++it) {
    int idx = it * 256 + tid;
    if (idx < 640) {
      int pair = idx >> 3, s8 = idx & 7;
      int c8 = s8 ^ (pair & 7);
      int row = pair * 2 + (c8 >> 2), j = c8 & 3;
      srcB[it] = Wb + (size_t)row * K_TOTAL + kbase + (j << 3);
      dstB[it] = (it * 256 + (tid & 192)) << 3;
    } else {
      srcB[it] = Wb; dstB[it] = 0;        // never issued (guarded below)
    }
  }

  // pooling: 4 threads per A-row; slots {(row+part)&7, +4} cover all 8 chunks
  const int prow = tid >> 2;
  const int part = tid & 3;
  const int ps1 = (prow + part) & 7;
  const int ps2 = (ps1 + 4) & 7;
  const int pm = m0 + prow;
  const int pool_base = (pm < M_TOTAL) ? ((pm / V_DIM) - b_first) * 16 : -1;

  // per-wave loads/chunk: A=2, B=3 (waves 0,1) or 2 (waves 2,3) -> K=5 or 4
#define ISSUE(c, bb)                                                          \
  {                                                                           \
    _Pragma("unroll")                                                         \
    for (int it = 0; it < 2; ++it)                                            \
      gl_lds16(srcA[it] + (c) * BK, &ldsA[bb][dstA[it]]);                     \
    _Pragma("unroll")                                                         \
    for (int it = 0; it < 2; ++it)                                            \
      gl_lds16(srcB[it] + (c) * BK, &ldsB[bb][dstB[it]]);                     \
    if (tid < 128) gl_lds16(srcB[2] + (c) * BK, &ldsB[bb][dstB[2]]);          \
  }

  floatx4 acc[10];
  #pragma unroll
  for (int nt = 0; nt < 10; ++nt) acc[nt] = (floatx4)(0.0f);

  ISSUE(0, 0);
  ISSUE(1, 1);                 // 2 chunks in flight (2K per wave)
  // publish lds_pool zeros: each wave drains its own ds_writes; the first
  // barrier below then orders them before any wave's first atomicAdd.
  asm volatile("s_waitcnt lgkmcnt(0)" ::: "memory");

  #pragma unroll 4
  for (int c = 0; c < CHUNKS; ++c) {
    const int buf = c & 3;
    // counted wait: drain to K (next chunk's loads stay in flight)
    if (c + 1 < CHUNKS) {
      if (wave < 2) asm volatile("s_waitcnt vmcnt(5)" ::: "memory");
      else          asm volatile("s_waitcnt vmcnt(4)" ::: "memory");
    } else {
      asm volatile("s_waitcnt vmcnt(0)" ::: "memory");
    }
    __builtin_amdgcn_sched_barrier(0);
    __builtin_amdgcn_s_barrier();        // chunk c's tile visible to all waves
    __builtin_amdgcn_sched_barrier(0);
    // issue c+2 into buf (c+2)&3: last read at chunk c-2 -> 2 barriers ago
    if (c + 2 < CHUNKS) ISSUE(c + 2, (c + 2) & 3);
    // pooling over this chunk's fp32 A tile (swizzle-invariant row sums)
    {
      const floatx4* aT = (const floatx4*)ldsA[buf];
      floatx4 u = aT[prow * 8 + ps1];
      floatx4 w = aT[prow * 8 + ps2];
      float s = ((u[0] + u[1]) + (u[2] + u[3])) + ((w[0] + w[1]) + (w[2] + w[3]));
      s += __shfl_down(s, 2, 4);
      s += __shfl_down(s, 1, 4);
      if (part == 0 && pool_base >= 0)
        atomicAdd(&lds_pool[pool_base + (c >> 1)], s);
    }
    // MFMA: A fragment read via swizzled slots, cvt to bf16 (reused 10x)
    {
      const floatx4* aT = (const floatx4*)ldsA[buf];
      const int r = wave * 16 + l16;
      floatx4 f0 = aT[r * 8 + ((2 * quad) ^ (r & 7))];
      floatx4 f1 = aT[r * 8 + ((2 * quad + 1) ^ (r & 7))];
      union { short8 s; unsigned int u[4]; } av;
      av.u[0] = cvt_pk_bf16(f0[0], f0[1]);
      av.u[1] = cvt_pk_bf16(f0[2], f0[3]);
      av.u[2] = cvt_pk_bf16(f1[0], f1[1]);
      av.u[3] = cvt_pk_bf16(f1[2], f1[3]);
      const short8* bT = (const short8*)ldsB[buf];
      #pragma unroll
      for (int nt = 0; nt < 10; ++nt) {
        int r2 = nt * 16 + l16;
        int pr = r2 >> 1;
        short8 b = bT[pr * 8 + ((((r2 & 1) << 2) | quad) ^ (pr & 7))];
        acc[nt] = __builtin_amdgcn_mfma_f32_16x16x32_bf16(av.s, b, acc[nt], 0, 0, 0);
      }
    }
  }

  __syncthreads();             // drains pool atomics; all reads done

  // partial-plane store (D layout: col=lane&15, row=quad*4+reg)
  {
    const int mrow = m0 + wave * 16 + quad * 4;
    float* Pp = P + (size_t)ky * SMN + (size_t)mrow * N_TOTAL + l16;
    #pragma unroll
    for (int r = 0; r < 4; ++r)
      if (mrow + r < M_TOTAL)
        #pragma unroll
        for (int nt = 0; nt < 10; ++nt)
          Pp[(size_t)r * N_TOTAL + nt * 16] = acc[nt][r];
  }

  // pooled partials: unique owner (mb, bl, d) -> plain store, no atomics
  if (tid < 80) {
    int bl = tid >> 4, dl = tid & 15;
    pp[((size_t)(mb * 5 + bl)) * D_DIM + d_first + dl] = lds_pool[tid];
  }
}

// ---------------- router: gather pooled from pp, MLP + softmax + top-2 ------
__global__ __launch_bounds__(256)
void router_kernel(const float* __restrict__ pp, const float* __restrict__ W1,
                   const float* __restrict__ b1, const float* __restrict__ W2,
                   const float* __restrict__ b2, float* __restrict__ wfull,
                   float* __restrict__ probs_out) {
  __shared__ float sp[D_DIM];
  __shared__ float sh[H_DIM];
  __shared__ float slog[E_DIM];
  const int b = blockIdx.x;
  const int t = threadIdx.x;
  // rows of batch b live in m-blocks mb1..mb2 (at most 2)
  const int mb1 = (b * V_DIM) / BM;
  const int mb2 = (b * V_DIM + V_DIM - 1) / BM;
  const int bf1 = (mb1 * BM) / V_DIM;
  const int bf2 = (mb2 * BM) / V_DIM;
  const float* p1 = pp + (size_t)(mb1 * 5 + (b - bf1)) * D_DIM;
  const float* p2 = pp + (size_t)(mb2 * 5 + (b - bf2)) * D_DIM;
  for (int d = t; d < D_DIM; d += 256) {
    float v = p1[d];
    if (mb2 != mb1) v += p2[d];
    sp[d] = v * POOL_SCALE;
  }
  __syncthreads();
  float acc = b1[t];
  const float* w1r = W1 + (size_t)t * D_DIM;
  for (int d = 0; d < D_DIM; ++d) acc += sp[d] * w1r[d];
  sh[t] = fmaxf(acc, 0.0f);
  __syncthreads();
  if (t < E_DIM) {
    float a = b2[t];
    const float* w2r = W2 + t * H_DIM;
    for (int j = 0; j < H_DIM; ++j) a += sh[j] * w2r[j];
    slog[t] = a;
  }
  __syncthreads();
  if (t == 0) {
    float p[E_DIM];
    float mx = slog[0];
    for (int e = 1; e < E_DIM; ++e) mx = fmaxf(mx, slog[e]);
    float se = 0.0f;
    for (int e = 0; e < E_DIM; ++e) { p[e] = __expf(slog[e] - mx); se += p[e]; }
    float inv = 1.0f / se;
    for (int e = 0; e < E_DIM; ++e) { p[e] *= inv; probs_out[b * E_DIM + e] = p[e]; }
    // top-2, lowest index wins ties (strict > keeps earlier index)
    int i0 = 0;
    for (int e = 1; e < E_DIM; ++e) if (p[e] > p[i0]) i0 = e;
    int i1 = (i0 == 0) ? 1 : 0;
    for (int e = 0; e < E_DIM; ++e) if (e != i0 && p[e] > p[i1]) i1 = e;
    float s2 = p[i0] + p[i1];
    float invs = 1.0f / fmaxf(s2, 1e-6f);
    for (int e = 0; e < E_DIM; ++e) {
      float w = 0.0f;
      if (e == i0) w += p[i0] * invs;
      if (e == i1) w += p[i1] * invs;
      wfull[b * E_DIM + e] = w;
    }
  }
}

// ------- reduce partials over KSPLIT + combine: out = S_b + b_base + 2*Σ w·(S_l·B)
__global__ __launch_bounds__(256)
void reduce_combine_kernel(const float* __restrict__ P, const float* __restrict__ b_base,
                           const float* __restrict__ lora_B, const float* __restrict__ wfull,
                           float* __restrict__ out) {
  __shared__ float sS[RC_ROWS * N_TOTAL];   // 640 floats
  const int t = threadIdx.x;
  const int NF4 = RC_ROWS * N_TOTAL / 4;    // 160 float4 per block
  if (t < NF4) {
    const floatx4* P4 = (const floatx4*)P;
    size_t base = (size_t)blockIdx.x * NF4 + t;
    floatx4 a = (floatx4)(0.0f);
    #pragma unroll 8
    for (int k = 0; k < KSPLIT; ++k) a += P4[(size_t)k * (SMN / 4) + base];
    *(floatx4*)&sS[t * 4] = a;
  }
  __syncthreads();
  for (int i = t; i < RC_ROWS * OUT_DIM; i += 256) {
    int mr = i / OUT_DIM;
    int o = i - mr * OUT_DIM;
    int mm = blockIdx.x * RC_ROWS + mr;
    int b = mm / V_DIM;
    const float* srow = sS + mr * N_TOTAL;
    float res = srow[o] + b_base[o];
    float moe = 0.0f;
    #pragma unroll
    for (int e = 0; e < E_DIM; ++e) {
      float we = wfull[b * E_DIM + e];
      if (we != 0.0f) {
        const float* lb = lora_B + ((size_t)e * OUT_DIM + o) * R_DIM;
        float dd = 0.0f;
        #pragma unroll
        for (int r = 0; r < R_DIM; ++r) dd += srow[OUT_DIM + e * R_DIM + r] * lb[r];
        moe += we * dd;
      }
    }
    out[(size_t)mm * OUT_DIM + o] = res + SCALING * moe;
  }
}

extern "C" void kernel_launch(void* const* d_in, const int* in_sizes, int n_in,
                              void* d_out, int out_size, void* d_ws, size_t ws_size,
                              hipStream_t stream) {
  const float* x      = (const float*)d_in[0];
  const float* W_base = (const float*)d_in[1];
  const float* b_base = (const float*)d_in[2];
  const float* W1     = (const float*)d_in[3];
  const float* b1     = (const float*)d_in[4];
  const float* W2     = (const float*)d_in[5];
  const float* b2     = (const float*)d_in[6];
  const float* lora_A = (const float*)d_in[7];
  const float* lora_B = (const float*)d_in[8];
  float* out = (float*)d_out;

  // ws layout: pp[11*5*512 f] | wfull[256 f] | Wb[160*32768 bf16] | P[32*107520 f]
  float* ws    = (float*)d_ws;
  float* pp    = ws;
  float* wfull = ws + NMB * 5 * D_DIM;
  short* Wb    = (short*)(wfull + 256);
  float* P     = (float*)(Wb + (size_t)N_TOTAL * K_TOTAL);

  convW_kernel<<<(N_TOTAL * K_TOTAL / 8 + 255) / 256, 256, 0, stream>>>(
      W_base, lora_A, Wb);
  gemm_kernel<<<dim3(NMB, KSPLIT), 256, 0, stream>>>(x, Wb, P, pp);
  router_kernel<<<B_DIM, 256, 0, stream>>>(pp, W1, b1, W2, b2, wfull,
                                           out + (size_t)M_TOTAL * OUT_DIM);
  reduce_combine_kernel<<<M_TOTAL / RC_ROWS, 256, 0, stream>>>(
      P, b_base, lora_B, wfull, out);
}

// Round 6
// 214.552 us; speedup vs baseline: 1.0111x; 1.0039x over previous
//
#include <hip/hip_runtime.h>

// Problem constants
#define B_DIM 32
#define V_DIM 21
#define D_DIM 512
#define P_DIM 64
#define M_TOTAL 672          // B*V
#define K_TOTAL 32768        // D*P
#define OUT_DIM 96
#define E_DIM 8
#define R_DIM 8
#define H_DIM 256
#define N_TOTAL 160          // OUT_DIM + E*R
#define SCALING 2.0f
#define POOL_SCALE (1.0f / (V_DIM * (float)P_DIM))

// GEMM: A = register stream (barrier-free); B = 4-buffer async LDS, counted vmcnt.
#define BM 64
#define BK 32
#define KSPLIT 32
#define K_PER_SPLIT (K_TOTAL / KSPLIT)   // 1024
#define CHUNKS (K_PER_SPLIT / BK)        // 32
#define SMN (M_TOTAL * N_TOTAL)          // 107520 per partial plane
#define NMB 11                           // m-blocks
#define RC_ROWS 4                        // rows per reduce_combine block

typedef __attribute__((ext_vector_type(4))) float floatx4;
typedef __attribute__((ext_vector_type(8))) short short8;

__device__ __forceinline__ unsigned short f2bf(float f) {
  union { float f; unsigned int u; } v; v.f = f;
  unsigned int u = v.u + (0x7FFFu + ((v.u >> 16) & 1u));  // RNE
  return (unsigned short)(u >> 16);
}

// v_cvt_pk_bf16_f32: RNE, lo -> bits[15:0], hi -> bits[31:16] (matches f2bf)
__device__ __forceinline__ unsigned int cvt_pk_bf16(float lo, float hi) {
  unsigned int r;
  asm("v_cvt_pk_bf16_f32 %0, %1, %2" : "=v"(r) : "v"(lo), "v"(hi));
  return r;
}

// async 16B global->LDS; lds ptr must be wave-uniform (HW adds lane*16)
__device__ __forceinline__ void gl_lds16(const void* g, void* l) {
  __builtin_amdgcn_global_load_lds(
      (const __attribute__((address_space(1))) void*)g,
      (__attribute__((address_space(3))) void*)l, 16, 0, 0);
}

__device__ __forceinline__ short8 as_s8(floatx4 v) {
  union { floatx4 f; short8 s; } u; u.f = v; return u.s;
}

// ------- convW: [W_base|lora_A] fp32 -> bf16 Wb[160][32768]
__global__ __launch_bounds__(256)
void convW_kernel(const float* __restrict__ W_base, const float* __restrict__ lora_A,
                  short* __restrict__ Wb) {
  int gid = blockIdx.x * 256 + threadIdx.x;
  size_t base = (size_t)gid * 8;
  int row = (int)(base >> 15);
  int k = (int)(base & 32767);
  const float* src = (row < OUT_DIM) ? (W_base + ((size_t)row << 15) + k)
                                     : (lora_A + ((size_t)(row - OUT_DIM) << 15) + k);
  floatx4 v0 = ((const floatx4*)src)[0];
  floatx4 v1 = ((const floatx4*)src)[1];
  short8 sv;
  sv[0] = (short)f2bf(v0[0]); sv[1] = (short)f2bf(v0[1]);
  sv[2] = (short)f2bf(v0[2]); sv[3] = (short)f2bf(v0[3]);
  sv[4] = (short)f2bf(v1[0]); sv[5] = (short)f2bf(v1[1]);
  sv[6] = (short)f2bf(v1[2]); sv[7] = (short)f2bf(v1[3]);
  *(short8*)(Wb + base) = sv;
}

// ------- gemm v6: A streamed to REGISTERS (depth-4, barrier-free, compiler-
// paced vmcnt) -- the MFMA A-fragment is exactly 2 contiguous dwordx4/lane.
// Pooling in registers (shfl per chunk-pair). B via gl_lds into 4 buffers,
// depth-3, hand-counted vmcnt (loop VMEM = 2 A-loads + kw gl_lds per wave,
// order pinned by sched_barrier); B-frags via volatile asm ds_read_b128
// (no compiler LDS-DMA alias stalls), conflict-free layout (no swizzle
// needed: 64 lanes hit 64 distinct 16B slots). XCD-grouped bid remap: 11
// consecutive same-XCD blocks share one 320KB B k-slice in L2.
// LDS 40.3 KB; grid 352x1.
__global__ __launch_bounds__(256, 2)
void gemm_kernel(const float* __restrict__ x, const short* __restrict__ Wb,
                 float* __restrict__ P, float* __restrict__ pp) {
  __shared__ __attribute__((aligned(16))) short ldsB[4][N_TOTAL * BK]; // 4 x 10 KB
  __shared__ float lds_pool[5 * 16];      // [b_local][d_local]

  const int tid = threadIdx.x;
  // XCD-grouped remap: xcd = bid%8 fixed -> same ky for 11 consecutive blocks
  const int bid = blockIdx.x;
  const int xcd = bid & 7;
  const int grp = bid >> 3;               // 0..43
  const int ky  = xcd + 8 * (grp / NMB);  // 0..31
  const int mb  = grp % NMB;              // 0..10
  const int m0 = mb * BM;
  const int kbase = ky * K_PER_SPLIT;
  const int lane = tid & 63;
  const int wave = tid >> 6;
  const int quad = lane >> 4;
  const int l16 = lane & 15;
  const int b_first = m0 / V_DIM;

  if (tid < 80) lds_pool[tid] = 0.0f;
  asm volatile("s_waitcnt lgkmcnt(0)" ::: "memory");   // publish zeros via 1st barrier

  // ---- A: per-lane register stream. lane(l16,quad) owns row m0+wave*16+l16,
  // k-window quad*8; chunk c = aptr[c*8], aptr[c*8+1] (offsets fold to imm).
  const int arow_raw = m0 + wave * 16 + l16;
  const bool row_ok = (arow_raw < M_TOTAL);
  const int arow = row_ok ? arow_raw : (M_TOTAL - 1);
  const floatx4* aptr =
      (const floatx4*)(x + (size_t)arow * K_TOTAL + kbase + quad * 8);

  // ---- B: DMA descriptors (linear). 640 x 16B chunks per tile:
  // idx=it*256+tid -> pair=idx>>3, s8=idx&7, row=2*pair+(s8>>2), col=s8&3.
  const short* srcB0; const short* srcB1; const short* srcB2 = Wb;
  int dstB0, dstB1, dstB2 = 0;
  {
    int idx = tid, pair = idx >> 3, s8 = idx & 7;
    srcB0 = Wb + (size_t)(2 * pair + (s8 >> 2)) * K_TOTAL + kbase + (s8 & 3) * 8;
    dstB0 = (tid & 192) << 3;
    idx = 256 + tid; pair = idx >> 3; s8 = idx & 7;
    srcB1 = Wb + (size_t)(2 * pair + (s8 >> 2)) * K_TOTAL + kbase + (s8 & 3) * 8;
    dstB1 = (256 + (tid & 192)) << 3;
    if (tid < 128) {
      idx = 512 + tid; pair = idx >> 3; s8 = idx & 7;
      srcB2 = Wb + (size_t)(2 * pair + (s8 >> 2)) * K_TOTAL + kbase + (s8 & 3) * 8;
      dstB2 = (512 + (tid & 192)) << 3;
    }
  }
  // per-lane LDS byte address of this lane's B slot (row pr=l16>>1 pair,
  // slot ((l16&1)<<2)|quad); nt -> +nt*1024; buffer -> +bb*10240.
  const unsigned baddr =
      (unsigned)(size_t)(__attribute__((address_space(3))) short*)&ldsB[0][0] +
      (unsigned)((l16 >> 1) * 128 + ((((l16 & 1) << 2) | quad) * 16));

#define ISSUE_B(c, bb)                                                        \
  {                                                                           \
    gl_lds16(srcB0 + (c) * BK, &ldsB[bb][dstB0]);                             \
    gl_lds16(srcB1 + (c) * BK, &ldsB[bb][dstB1]);                             \
    if (tid < 128) gl_lds16(srcB2 + (c) * BK, &ldsB[bb][dstB2]);              \
  }
#define WAITV(N) asm volatile("s_waitcnt vmcnt(" #N ")" ::: "memory")
#define SBAR __builtin_amdgcn_sched_barrier(0)

  floatx4 af[4][2];
  floatx4 acc[10];
  #pragma unroll
  for (int nt = 0; nt < 10; ++nt) acc[nt] = (floatx4)(0.0f);
  floatx4 paccv = (floatx4)(0.0f);

  // prologue, order-pinned: [B0 A0][B1 A1][B2 A2][A3]
  ISSUE_B(0, 0); SBAR;
  af[0][0] = aptr[0];  af[0][1] = aptr[1];  SBAR;
  ISSUE_B(1, 1); SBAR;
  af[1][0] = aptr[8];  af[1][1] = aptr[9];  SBAR;
  ISSUE_B(2, 2); SBAR;
  af[2][0] = aptr[16]; af[2][1] = aptr[17];
  af[3][0] = aptr[24]; af[3][1] = aptr[25];

  #pragma unroll
  for (int c = 0; c < CHUNKS; ++c) {
    const int bb = c & 3;
    // counted wait: retire [A(c), B(c)], keep 2-3 chunks of B + 4 of A in flight
    if (c <= CHUNKS - 4)      { if (wave < 2) WAITV(12); else WAITV(10); }
    else if (c == CHUNKS - 3) { if (wave < 2) WAITV(10); else WAITV(8); }
    else if (c == CHUNKS - 2) { if (wave < 2) WAITV(5);  else WAITV(4); }
    else                      { WAITV(0); }
    SBAR;
    __builtin_amdgcn_s_barrier();        // B(c) visible to all waves
    SBAR;
    if (c + 3 < CHUNKS) ISSUE_B(c + 3, (c + 3) & 3);
    SBAR;                                // pin [B issues][A issue] order
    // A fragment: cvt + pooling from af[bb], then refill af[bb] with c+4
    floatx4 f0 = af[bb][0], f1 = af[bb][1];
    union { short8 s; unsigned int u[4]; } av;
    av.u[0] = cvt_pk_bf16(f0[0], f0[1]);
    av.u[1] = cvt_pk_bf16(f0[2], f0[3]);
    av.u[2] = cvt_pk_bf16(f1[0], f1[1]);
    av.u[3] = cvt_pk_bf16(f1[2], f1[3]);
    paccv += f0 + f1;
    if (c & 1) {                         // d-boundary: flush row-sum for d=c>>1
      float h = (paccv[0] + paccv[1]) + (paccv[2] + paccv[3]);
      h += __shfl_down(h, 32);
      h += __shfl_down(h, 16);
      if (lane < 16 && row_ok)
        atomicAdd(&lds_pool[(arow / V_DIM - b_first) * 16 + (c >> 1)], h);
      paccv = (floatx4)(0.0f);
    }
    if (c + 4 < CHUNKS) {
      af[bb][0] = aptr[(c + 4) * 8];
      af[bb][1] = aptr[(c + 4) * 8 + 1];
    }
    // B fragments: 10 raw ds_read_b128 (no compiler LDS-DMA alias waits)
    const unsigned ba = baddr + (unsigned)(bb * (N_TOTAL * BK * 2));
    floatx4 b0, b1, b2, b3, b4, b5, b6, b7, b8, b9;
    asm volatile("ds_read_b128 %0, %1 offset:0"    : "=&v"(b0) : "v"(ba));
    asm volatile("ds_read_b128 %0, %1 offset:1024" : "=&v"(b1) : "v"(ba));
    asm volatile("ds_read_b128 %0, %1 offset:2048" : "=&v"(b2) : "v"(ba));
    asm volatile("ds_read_b128 %0, %1 offset:3072" : "=&v"(b3) : "v"(ba));
    asm volatile("ds_read_b128 %0, %1 offset:4096" : "=&v"(b4) : "v"(ba));
    asm volatile("ds_read_b128 %0, %1 offset:5120" : "=&v"(b5) : "v"(ba));
    asm volatile("ds_read_b128 %0, %1 offset:6144" : "=&v"(b6) : "v"(ba));
    asm volatile("ds_read_b128 %0, %1 offset:7168" : "=&v"(b7) : "v"(ba));
    asm volatile("ds_read_b128 %0, %1 offset:8192" : "=&v"(b8) : "v"(ba));
    asm volatile("ds_read_b128 %0, %1 offset:9216" : "=&v"(b9) : "v"(ba));
    asm volatile("s_waitcnt lgkmcnt(0)" ::: "memory");
    SBAR;                                // rule 18: keep MFMAs below the wait
    acc[0] = __builtin_amdgcn_mfma_f32_16x16x32_bf16(av.s, as_s8(b0), acc[0], 0, 0, 0);
    acc[1] = __builtin_amdgcn_mfma_f32_16x16x32_bf16(av.s, as_s8(b1), acc[1], 0, 0, 0);
    acc[2] = __builtin_amdgcn_mfma_f32_16x16x32_bf16(av.s, as_s8(b2), acc[2], 0, 0, 0);
    acc[3] = __builtin_amdgcn_mfma_f32_16x16x32_bf16(av.s, as_s8(b3), acc[3], 0, 0, 0);
    acc[4] = __builtin_amdgcn_mfma_f32_16x16x32_bf16(av.s, as_s8(b4), acc[4], 0, 0, 0);
    acc[5] = __builtin_amdgcn_mfma_f32_16x16x32_bf16(av.s, as_s8(b5), acc[5], 0, 0, 0);
    acc[6] = __builtin_amdgcn_mfma_f32_16x16x32_bf16(av.s, as_s8(b6), acc[6], 0, 0, 0);
    acc[7] = __builtin_amdgcn_mfma_f32_16x16x32_bf16(av.s, as_s8(b7), acc[7], 0, 0, 0);
    acc[8] = __builtin_amdgcn_mfma_f32_16x16x32_bf16(av.s, as_s8(b8), acc[8], 0, 0, 0);
    acc[9] = __builtin_amdgcn_mfma_f32_16x16x32_bf16(av.s, as_s8(b9), acc[9], 0, 0, 0);
  }

  __syncthreads();             // drain pool atomics; everything retired

  // partial-plane store (D layout: col=lane&15, row=quad*4+reg)
  {
    const int mrow = m0 + wave * 16 + quad * 4;
    float* Pp = P + (size_t)ky * SMN + (size_t)mrow * N_TOTAL + l16;
    #pragma unroll
    for (int r = 0; r < 4; ++r)
      if (mrow + r < M_TOTAL)
        #pragma unroll
        for (int nt = 0; nt < 10; ++nt)
          Pp[(size_t)r * N_TOTAL + nt * 16] = acc[nt][r];
  }

  // pooled partials: unique owner (mb, bl, d) -> plain store, no atomics
  if (tid < 80) {
    int bl = tid >> 4, dl = tid & 15;
    pp[((size_t)(mb * 5 + bl)) * D_DIM + ky * 16 + dl] = lds_pool[tid];
  }
}

// ---------------- router: gather pooled from pp, MLP + softmax + top-2 ------
__global__ __launch_bounds__(256)
void router_kernel(const float* __restrict__ pp, const float* __restrict__ W1,
                   const float* __restrict__ b1, const float* __restrict__ W2,
                   const float* __restrict__ b2, float* __restrict__ wfull,
                   float* __restrict__ probs_out) {
  __shared__ float sp[D_DIM];
  __shared__ float sh[H_DIM];
  __shared__ float slog[E_DIM];
  const int b = blockIdx.x;
  const int t = threadIdx.x;
  // rows of batch b live in m-blocks mb1..mb2 (at most 2)
  const int mb1 = (b * V_DIM) / BM;
  const int mb2 = (b * V_DIM + V_DIM - 1) / BM;
  const int bf1 = (mb1 * BM) / V_DIM;
  const int bf2 = (mb2 * BM) / V_DIM;
  const float* p1 = pp + (size_t)(mb1 * 5 + (b - bf1)) * D_DIM;
  const float* p2 = pp + (size_t)(mb2 * 5 + (b - bf2)) * D_DIM;
  for (int d = t; d < D_DIM; d += 256) {
    float v = p1[d];
    if (mb2 != mb1) v += p2[d];
    sp[d] = v * POOL_SCALE;
  }
  __syncthreads();
  float acc = b1[t];
  const float* w1r = W1 + (size_t)t * D_DIM;
  for (int d = 0; d < D_DIM; ++d) acc += sp[d] * w1r[d];
  sh[t] = fmaxf(acc, 0.0f);
  __syncthreads();
  if (t < E_DIM) {
    float a = b2[t];
    const float* w2r = W2 + t * H_DIM;
    for (int j = 0; j < H_DIM; ++j) a += sh[j] * w2r[j];
    slog[t] = a;
  }
  __syncthreads();
  if (t == 0) {
    float p[E_DIM];
    float mx = slog[0];
    for (int e = 1; e < E_DIM; ++e) mx = fmaxf(mx, slog[e]);
    float se = 0.0f;
    for (int e = 0; e < E_DIM; ++e) { p[e] = __expf(slog[e] - mx); se += p[e]; }
    float inv = 1.0f / se;
    for (int e = 0; e < E_DIM; ++e) { p[e] *= inv; probs_out[b * E_DIM + e] = p[e]; }
    // top-2, lowest index wins ties (strict > keeps earlier index)
    int i0 = 0;
    for (int e = 1; e < E_DIM; ++e) if (p[e] > p[i0]) i0 = e;
    int i1 = (i0 == 0) ? 1 : 0;
    for (int e = 0; e < E_DIM; ++e) if (e != i0 && p[e] > p[i1]) i1 = e;
    float s2 = p[i0] + p[i1];
    float invs = 1.0f / fmaxf(s2, 1e-6f);
    for (int e = 0; e < E_DIM; ++e) {
      float w = 0.0f;
      if (e == i0) w += p[i0] * invs;
      if (e == i1) w += p[i1] * invs;
      wfull[b * E_DIM + e] = w;
    }
  }
}

// ------- reduce partials over KSPLIT + combine: out = S_b + b_base + 2*Σ w·(S_l·B)
__global__ __launch_bounds__(256)
void reduce_combine_kernel(const float* __restrict__ P, const float* __restrict__ b_base,
                           const float* __restrict__ lora_B, const float* __restrict__ wfull,
                           float* __restrict__ out) {
  __shared__ float sS[RC_ROWS * N_TOTAL];   // 640 floats
  const int t = threadIdx.x;
  const int NF4 = RC_ROWS * N_TOTAL / 4;    // 160 float4 per block
  if (t < NF4) {
    const floatx4* P4 = (const floatx4*)P;
    size_t base = (size_t)blockIdx.x * NF4 + t;
    floatx4 a = (floatx4)(0.0f);
    #pragma unroll 8
    for (int k = 0; k < KSPLIT; ++k) a += P4[(size_t)k * (SMN / 4) + base];
    *(floatx4*)&sS[t * 4] = a;
  }
  __syncthreads();
  for (int i = t; i < RC_ROWS * OUT_DIM; i += 256) {
    int mr = i / OUT_DIM;
    int o = i - mr * OUT_DIM;
    int mm = blockIdx.x * RC_ROWS + mr;
    int b = mm / V_DIM;
    const float* srow = sS + mr * N_TOTAL;
    float res = srow[o] + b_base[o];
    float moe = 0.0f;
    #pragma unroll
    for (int e = 0; e < E_DIM; ++e) {
      float we = wfull[b * E_DIM + e];
      if (we != 0.0f) {
        const float* lb = lora_B + ((size_t)e * OUT_DIM + o) * R_DIM;
        float dd = 0.0f;
        #pragma unroll
        for (int r = 0; r < R_DIM; ++r) dd += srow[OUT_DIM + e * R_DIM + r] * lb[r];
        moe += we * dd;
      }
    }
    out[(size_t)mm * OUT_DIM + o] = res + SCALING * moe;
  }
}

extern "C" void kernel_launch(void* const* d_in, const int* in_sizes, int n_in,
                              void* d_out, int out_size, void* d_ws, size_t ws_size,
                              hipStream_t stream) {
  const float* x      = (const float*)d_in[0];
  const float* W_base = (const float*)d_in[1];
  const float* b_base = (const float*)d_in[2];
  const float* W1     = (const float*)d_in[3];
  const float* b1     = (const float*)d_in[4];
  const float* W2     = (const float*)d_in[5];
  const float* b2     = (const float*)d_in[6];
  const float* lora_A = (const float*)d_in[7];
  const float* lora_B = (const float*)d_in[8];
  float* out = (float*)d_out;

  // ws layout: pp[11*5*512 f] | wfull[256 f] | Wb[160*32768 bf16] | P[32*107520 f]
  float* ws    = (float*)d_ws;
  float* pp    = ws;
  float* wfull = ws + NMB * 5 * D_DIM;
  short* Wb    = (short*)(wfull + 256);
  float* P     = (float*)(Wb + (size_t)N_TOTAL * K_TOTAL);

  convW_kernel<<<(N_TOTAL * K_TOTAL / 8 + 255) / 256, 256, 0, stream>>>(
      W_base, lora_A, Wb);
  gemm_kernel<<<NMB * KSPLIT, 256, 0, stream>>>(x, Wb, P, pp);
  router_kernel<<<B_DIM, 256, 0, stream>>>(pp, W1, b1, W2, b2, wfull,
                                           out + (size_t)M_TOTAL * OUT_DIM);
  reduce_combine_kernel<<<M_TOTAL / RC_ROWS, 256, 0, stream>>>(
      P, b_base, lora_B, wfull, out);
}